// Round 6
// baseline (404.494 us; speedup 1.0000x reference)
//
#include <hip/hip_runtime.h>
#include <stdint.h>

typedef unsigned short u16;
typedef __attribute__((ext_vector_type(4))) unsigned short u16x4;
typedef __attribute__((ext_vector_type(8))) short bf16x8;
typedef __attribute__((ext_vector_type(4))) float f32x4;

#define PTOT 36864
#define WIMG 192

__device__ __forceinline__ float bf2f(u16 h) {
    union { uint32_t u; float f; } v; v.u = ((uint32_t)h) << 16; return v.f;
}
__device__ __forceinline__ u16 f2bf(float f) {
    union { float f; uint32_t u; } v; v.f = f;
    uint32_t u = v.u;
    return (u16)((u + 0x7FFFu + ((u >> 16) & 1u)) >> 16);
}

#define ASYNC_COPY16(gp, lp)                                                     \
    __builtin_amdgcn_global_load_lds(                                            \
        (const __attribute__((address_space(1))) void*)(gp),                     \
        (__attribute__((address_space(3))) void*)(lp), 16, 0, 0)

// ---------- transpose+convert: x (b,256,P) f32 -> xt (b,P,256) bf16 ----------
__global__ __launch_bounds__(256) void k_transpose(const float* __restrict__ x,
                                                   u16* __restrict__ xt) {
    __shared__ u16 tile[32][33];
    const int tx = threadIdx.x, ty = threadIdx.y;  // (32, 8)
    const int p0 = blockIdx.x * 32, c0 = blockIdx.y * 32, b = blockIdx.z;
    const float* src = x + (size_t)b * 256 * PTOT;
    u16* dst = xt + (size_t)b * PTOT * 256;
#pragma unroll
    for (int k = 0; k < 4; ++k) {
        int c = c0 + ty + k * 8;
        tile[ty + k * 8][tx] = f2bf(src[(size_t)c * PTOT + p0 + tx]);
    }
    __syncthreads();
#pragma unroll
    for (int k = 0; k < 4; ++k) {
        int p = p0 + ty + k * 8;
        dst[(size_t)p * 256 + c0 + tx] = tile[tx][ty + k * 8];
    }
}

// ---------- f32 -> bf16 elementwise (weights) ----------
__global__ void k_f2bf(const float* __restrict__ src, u16* __restrict__ dst, int n) {
    int i = blockIdx.x * 256 + threadIdx.x;
    if (i < n) dst[i] = f2bf(src[i]);
}

// ---------- GEMM: C[b,row,p] = sum_c A[row,c] * Bt[b,p,c] + bias[row] ----------
template <bool OUT_F32>
__global__ __launch_bounds__(256) void k_gemm(const u16* __restrict__ A,
                                              const u16* __restrict__ Bt,
                                              void* __restrict__ Cout,
                                              const float* __restrict__ bias,
                                              int M) {
    __shared__ u16 As[128 * 32];
    __shared__ u16 Bs[128 * 32];
    const int tid = threadIdx.x;
    const int lane = tid & 63;
    const int wave = tid >> 6;
    const int wr = wave >> 1, wc = wave & 1;
    const int nb = blockIdx.x, mb = blockIdx.y, b = blockIdx.z;

    const u16* Ab = A + (size_t)(mb * 128) * 256;
    const u16* Bb = Bt + ((size_t)b * PTOT + (size_t)nb * 128) * 256;

    const int lrow = lane >> 2;
    const int lcol = (lane & 3) * 8;
    const int lr = lane & 15;
    const int lk = lane >> 4;

    f32x4 acc[4][4];
#pragma unroll
    for (int m = 0; m < 4; ++m)
#pragma unroll
        for (int n = 0; n < 4; ++n) acc[m][n] = (f32x4)0.f;

    for (int k0 = 0; k0 < 256; k0 += 32) {
        __syncthreads();
        const int i0 = wave * 2;
#pragma unroll
        for (int ii = 0; ii < 2; ++ii) {
            const int i = i0 + ii;
            ASYNC_COPY16(Ab + (size_t)(i * 16 + lrow) * 256 + k0 + lcol,
                         As + i * 16 * 32);
            ASYNC_COPY16(Bb + (size_t)(i * 16 + lrow) * 256 + k0 + lcol,
                         Bs + i * 16 * 32);
        }
        __syncthreads();
        const bf16x8* Asv = (const bf16x8*)As;
        const bf16x8* Bsv = (const bf16x8*)Bs;
        bf16x8 afr[4], bfr[4];
#pragma unroll
        for (int m = 0; m < 4; ++m)
            afr[m] = Asv[(wr * 64 + m * 16 + lr) * 4 + lk];
#pragma unroll
        for (int n = 0; n < 4; ++n)
            bfr[n] = Bsv[(wc * 64 + n * 16 + lr) * 4 + lk];
#pragma unroll
        for (int m = 0; m < 4; ++m)
#pragma unroll
            for (int n = 0; n < 4; ++n)
                acc[m][n] = __builtin_amdgcn_mfma_f32_16x16x32_bf16(
                    afr[m], bfr[n], acc[m][n], 0, 0, 0);
    }

    const int cr = (lane >> 4) * 4;
    const int cc = lane & 15;
#pragma unroll
    for (int m = 0; m < 4; ++m) {
#pragma unroll
        for (int j = 0; j < 4; ++j) {
            const int row = mb * 128 + wr * 64 + m * 16 + cr + j;
            const float bv = bias[row];
            const size_t rbase =
                ((size_t)b * M + row) * PTOT + (size_t)nb * 128 + wc * 64 + cc;
#pragma unroll
            for (int n = 0; n < 4; ++n) {
                const float v = acc[m][n][j] + bv;
                if (OUT_F32)
                    ((float*)Cout)[rbase + n * 16] = v;
                else
                    ((u16*)Cout)[rbase + n * 16] = f2bf(v);
            }
        }
    }
}

// ---------- fused dwconv3x3 + windowed channel cross-attention ----------
// 2 windows (8x16 px) per block; ~33 KB LDS -> 4 blocks/CU.
// grid (288=24x12, 8, 2), 256 threads.
__global__ __launch_bounds__(256) void k_attn(const u16* __restrict__ qpre,
                                              const u16* __restrict__ kvpre,
                                              const float* __restrict__ w_dw,
                                              const float* __restrict__ b_dw,
                                              const float* __restrict__ w_dw2,
                                              const float* __restrict__ b_dw2,
                                              const float* __restrict__ temp,
                                              u16* __restrict__ outt) {
    // u16 units: Q[0,4624) K[4624,9248) VT[9248,14384) IQ@14384 IK@14512
    // SS(f32) overlays K; P overlays Q.  Score phase computes into regs,
    // barriers, THEN writes SS (two waves share a window's K -> must not
    // clobber K while the sibling wave still reads it).
    __shared__ __align__(16) u16 lds[14640];
    __shared__ float wb[960];  // [t:320][c:10] taps 0..8 + bias at 9
    u16* Q = lds;                 // [w:2312][c:72][64]
    u16* K = lds + 4624;
    u16* VT = lds + 9248;         // [w:2568][n:40][32]
    float* IQ = (float*)(lds + 14384);  // [w:2][32]
    float* IK = (float*)(lds + 14512);
    float* SS = (float*)(lds + 4624);   // [w:1156][c:36][32]
    u16* P = lds;                       // [w:1280][c:40][32]

    const int tid = threadIdx.x;
    const int lane = tid & 63;
    const int wv = tid >> 6;
    const int h = blockIdx.y, b = blockIdx.z;
    const int wy = blockIdx.x / 12, wxg = blockIdx.x % 12;
    const int px0 = wxg * 16;

    // ---- stage conv weights+bias to LDS ----
    for (int idx = tid; idx < 960; idx += 256) {
        const int t = idx / 320, r = idx - t * 320;
        const int c = r / 10, j = r - c * 10;
        const int ch = (t == 0 ? 0 : (t == 1 ? 256 : 512)) + h * 32 + c;
        const float* wsrc = (t == 0) ? w_dw : w_dw2;
        const float* bsrc = (t == 0) ? b_dw : b_dw2;
        wb[idx] = (j < 9) ? wsrc[ch * 9 + j] : bsrc[ch];
    }

    const size_t qbase = ((size_t)b * 256 + h * 32) * PTOT;
    const size_t kbase = ((size_t)b * 512 + h * 32) * PTOT;
    const size_t vbase = kbase + (size_t)256 * PTOT;
    __syncthreads();

    // ---- stage: on-the-fly dwconv3x3 -> Q,K row-major; V transposed ----
#pragma unroll
    for (int it = 0; it < 2; ++it) {
        const int L = it * 256 + tid;
        const int c = L >> 4, rem = L & 15, rr = rem >> 1, w = rem & 1;
        const int gy = wy * 8 + rr, gx = px0 + w * 8;
        float oq[8], ok[8], ov[8];
        {
            const float* wq10 = wb + c * 10;
            const float* wk10 = wb + 320 + c * 10;
            const float* wv10 = wb + 640 + c * 10;
#pragma unroll
            for (int i = 0; i < 8; ++i) {
                oq[i] = wq10[9]; ok[i] = wk10[9]; ov[i] = wv10[9];
            }
            const u16* qpl = qpre + qbase + (size_t)c * PTOT;
            const u16* kpl = kvpre + kbase + (size_t)c * PTOT;
            const u16* vpl = kvpre + vbase + (size_t)c * PTOT;
#pragma unroll
            for (int dy = -1; dy <= 1; ++dy) {
                const int yy = gy + dy;
                if ((unsigned)yy >= (unsigned)WIMG) continue;
                const int ro = yy * WIMG + gx;
                const int tap = (dy + 1) * 3;
#pragma unroll
                for (int t = 0; t < 3; ++t) {
                    const u16* row = (t == 0 ? qpl : (t == 1 ? kpl : vpl)) + ro;
                    float* acc = (t == 0 ? oq : (t == 1 ? ok : ov));
                    const float* w10 = (t == 0 ? wq10 : (t == 1 ? wk10 : wv10));
                    const bf16x8 cv = *(const bf16x8*)row;
                    float p[10];
                    p[0] = (gx > 0) ? bf2f(row[-1]) : 0.f;
                    p[9] = (gx < 184) ? bf2f(row[8]) : 0.f;
#pragma unroll
                    for (int i = 0; i < 8; ++i) p[i + 1] = bf2f((u16)cv[i]);
                    const float wa = w10[tap], wbv = w10[tap + 1], wcv = w10[tap + 2];
#pragma unroll
                    for (int i = 0; i < 8; ++i)
                        acc[i] += wa * p[i] + wbv * p[i + 1] + wcv * p[i + 2];
                }
            }
        }
        bf16x8 qv, kv8;
#pragma unroll
        for (int i = 0; i < 8; ++i) { qv[i] = (short)f2bf(oq[i]); kv8[i] = (short)f2bf(ok[i]); }
        *(bf16x8*)(Q + w * 2312 + c * 72 + rr * 8) = qv;
        *(bf16x8*)(K + w * 2312 + c * 72 + rr * 8) = kv8;
        u16* vt = VT + w * 2568 + rr * 8 * 40 + c;
#pragma unroll
        for (int j = 0; j < 8; ++j) vt[j * 40] = f2bf(ov[j]);
    }
    __syncthreads();

    // ---- row l2-norms: tid<64 -> Q rows, 64..127 -> K rows ----
    if (tid < 128) {
        const int t = tid >> 6, w = (tid >> 5) & 1, c = tid & 31;
        const u16* row = (t == 0 ? Q : K) + w * 2312 + c * 72;
        float s = 0.f;
#pragma unroll
        for (int j = 0; j < 8; ++j) {
            bf16x8 v = *(const bf16x8*)(row + j * 8);
#pragma unroll
            for (int i = 0; i < 8; ++i) { float f = bf2f((u16)v[i]); s += f * f; }
        }
        const float inv = 1.f / fmaxf(sqrtf(s), 1e-12f);
        (t == 0 ? IQ : IK)[w * 32 + c] = inv;
    }
    __syncthreads();

    // ---- scores: wave (hf,w) computes rows hf*16.. of window w's 32x32 ----
    {
        const int w = wv & 1, hf = wv >> 1;
        const int lr = lane & 15, lk = lane >> 4;
        f32x4 s0 = (f32x4)0.f, s1 = (f32x4)0.f;
        const u16* Qw = Q + w * 2312 + (hf * 16 + lr) * 72 + lk * 8;
        const u16* Kw = K + w * 2312 + lk * 8;
#pragma unroll
        for (int kb = 0; kb < 2; ++kb) {
            bf16x8 a = *(const bf16x8*)(Qw + kb * 32);
            bf16x8 b0 = *(const bf16x8*)(Kw + lr * 72 + kb * 32);
            bf16x8 b1 = *(const bf16x8*)(Kw + (16 + lr) * 72 + kb * 32);
            s0 = __builtin_amdgcn_mfma_f32_16x16x32_bf16(a, b0, s0, 0, 0, 0);
            s1 = __builtin_amdgcn_mfma_f32_16x16x32_bf16(a, b1, s1, 0, 0, 0);
        }
        // all waves' K reads must complete before SS (aliasing K) is written
        __syncthreads();
        float* srow = SS + w * 1156;
        const int cr = hf * 16 + lk * 4;
#pragma unroll
        for (int j = 0; j < 4; ++j) {
            srow[(cr + j) * 36 + lr] = s0[j];
            srow[(cr + j) * 36 + 16 + lr] = s1[j];
        }
    }
    __syncthreads();

    // ---- softmax: thread (w,c) owns one score row, fully in-register ----
    if (tid < 64) {
        const int w = tid >> 5, c = tid & 31;
        const float* srow = SS + w * 1156 + c * 36;
        const float* ik = IK + w * 32;
        const float iq = IQ[w * 32 + c] * temp[h];
        float sv[32];
        float mx = -1e30f;
#pragma unroll
        for (int d = 0; d < 32; ++d) {
            sv[d] = srow[d] * ik[d] * iq;
            mx = fmaxf(mx, sv[d]);
        }
        float sum = 0.f;
#pragma unroll
        for (int d = 0; d < 32; ++d) {
            sv[d] = __expf(sv[d] - mx);
            sum += sv[d];
        }
        const float inv = 1.f / sum;
        u16* prow = P + w * 1280 + c * 40;
#pragma unroll
        for (int ch = 0; ch < 4; ++ch) {
            bf16x8 pv;
#pragma unroll
            for (int i = 0; i < 8; ++i) pv[i] = (short)f2bf(sv[ch * 8 + i] * inv);
            *(bf16x8*)(prow + ch * 8) = pv;
        }
    }
    __syncthreads();

    // ---- PV: wave (hf,w) computes channels hf*16.. x 64 px of window w ----
    {
        const int w = wv & 1, hf = wv >> 1;
        const int lr = lane & 15, lk = lane >> 4;
        bf16x8 pa = *(const bf16x8*)(P + w * 1280 + (hf * 16 + lr) * 40 + lk * 8);
        f32x4 o[4];
#pragma unroll
        for (int ni = 0; ni < 4; ++ni) o[ni] = (f32x4)0.f;
#pragma unroll
        for (int ni = 0; ni < 4; ++ni) {
            bf16x8 vb = *(const bf16x8*)(VT + w * 2568 + (ni * 16 + lr) * 40 + lk * 8);
            o[ni] = __builtin_amdgcn_mfma_f32_16x16x32_bf16(pa, vb, o[ni], 0, 0, 0);
        }
#pragma unroll
        for (int ni = 0; ni < 4; ++ni) {
            const int n = ni * 16 + lr;
            const size_t gp = (size_t)(wy * 8 + (n >> 3)) * WIMG + px0 + w * 8 + (n & 7);
            u16* op = outt + ((size_t)b * PTOT + gp) * 256 + h * 32 + hf * 16 + lk * 4;
            u16x4 pk;
#pragma unroll
            for (int j = 0; j < 4; ++j) pk[j] = f2bf(o[ni][j]);
            *(u16x4*)op = pk;
        }
    }
}

extern "C" void kernel_launch(void* const* d_in, const int* in_sizes, int n_in,
                              void* d_out, int out_size, void* d_ws, size_t ws_size,
                              hipStream_t stream) {
    (void)in_sizes; (void)n_in; (void)out_size; (void)ws_size;
    const float* x      = (const float*)d_in[0];
    const float* x2     = (const float*)d_in[1];
    const float* w_qkv  = (const float*)d_in[2];
    const float* b_qkv  = (const float*)d_in[3];
    const float* w_dw   = (const float*)d_in[4];
    const float* b_dw   = (const float*)d_in[5];
    const float* w_qkv2 = (const float*)d_in[6];
    const float* b_qkv2 = (const float*)d_in[7];
    const float* w_dw2  = (const float*)d_in[8];
    const float* b_dw2  = (const float*)d_in[9];
    const float* temp   = (const float*)d_in[10];
    const float* w_proj = (const float*)d_in[11];
    const float* b_proj = (const float*)d_in[12];
    float* out = (float*)d_out;

    char* ws = (char*)d_ws;
    const size_t SZ_T  = (size_t)2 * PTOT * 256 * 2;
    const size_t SZ_KV = (size_t)2 * PTOT * 512 * 2;
    u16* xt     = (u16*)(ws);
    u16* x2t    = (u16*)(ws + SZ_T);
    u16* qpre   = (u16*)(ws + 2 * SZ_T);
    u16* kvpre  = (u16*)(ws + 3 * SZ_T);
    u16* wq     = (u16*)(ws + 3 * SZ_T + 2 * SZ_KV);
    u16* wkv    = wq + 256 * 256;
    u16* wproj  = wkv + 512 * 256;
    u16* attnt  = x2t;  // x2t dead after kv-GEMM

    const dim3 tb(32, 8);
    k_transpose<<<dim3(PTOT / 32, 8, 2), tb, 0, stream>>>(x, xt);
    k_transpose<<<dim3(PTOT / 32, 8, 2), tb, 0, stream>>>(x2, x2t);
    k_f2bf<<<(256 * 256 + 255) / 256, 256, 0, stream>>>(w_qkv, wq, 256 * 256);
    k_f2bf<<<(512 * 256 + 255) / 256, 256, 0, stream>>>(w_qkv2 + 256 * 256, wkv, 512 * 256);
    k_f2bf<<<(256 * 256 + 255) / 256, 256, 0, stream>>>(w_proj, wproj, 256 * 256);

    k_gemm<false><<<dim3(PTOT / 128, 2, 2), 256, 0, stream>>>(wq, xt, qpre, b_qkv, 256);
    k_gemm<false><<<dim3(PTOT / 128, 4, 2), 256, 0, stream>>>(wkv, x2t, kvpre, b_qkv2 + 256, 512);

    k_attn<<<dim3(288, 8, 2), 256, 0, stream>>>(qpre, kvpre, w_dw, b_dw,
                                                w_dw2, b_dw2, temp, attnt);

    k_gemm<true><<<dim3(PTOT / 128, 2, 2), 256, 0, stream>>>(wproj, attnt, out, b_proj, 256);
}

// Round 7
// 246.885 us; speedup vs baseline: 1.6384x; 1.6384x over previous
//
#include <hip/hip_runtime.h>
#include <stdint.h>

typedef unsigned short u16;
typedef __attribute__((ext_vector_type(4))) unsigned short u16x4;
typedef __attribute__((ext_vector_type(8))) short bf16x8;
typedef __attribute__((ext_vector_type(4))) float f32x4;

#define PTOT 36864
#define WIMG 192

__device__ __forceinline__ float bf2f(u16 h) {
    union { uint32_t u; float f; } v; v.u = ((uint32_t)h) << 16; return v.f;
}
__device__ __forceinline__ u16 f2bf(float f) {
    union { float f; uint32_t u; } v; v.f = f;
    uint32_t u = v.u;
    return (u16)((u + 0x7FFFu + ((u >> 16) & 1u)) >> 16);
}

#define ASYNC_COPY16(gp, lp)                                                     \
    __builtin_amdgcn_global_load_lds(                                            \
        (const __attribute__((address_space(1))) void*)(gp),                     \
        (__attribute__((address_space(3))) void*)(lp), 16, 0, 0)

// ---------- transpose+convert: x (b,256,P) f32 -> xt (b,P,256) bf16 ----------
__global__ __launch_bounds__(256) void k_transpose(const float* __restrict__ x,
                                                   u16* __restrict__ xt) {
    __shared__ u16 tile[32][33];
    const int tx = threadIdx.x, ty = threadIdx.y;  // (32, 8)
    const int p0 = blockIdx.x * 32, c0 = blockIdx.y * 32, b = blockIdx.z;
    const float* src = x + (size_t)b * 256 * PTOT;
    u16* dst = xt + (size_t)b * PTOT * 256;
#pragma unroll
    for (int k = 0; k < 4; ++k) {
        int c = c0 + ty + k * 8;
        tile[ty + k * 8][tx] = f2bf(src[(size_t)c * PTOT + p0 + tx]);
    }
    __syncthreads();
#pragma unroll
    for (int k = 0; k < 4; ++k) {
        int p = p0 + ty + k * 8;
        dst[(size_t)p * 256 + c0 + tx] = tile[tx][ty + k * 8];
    }
}

// ---------- f32 -> bf16 elementwise (weights) ----------
__global__ void k_f2bf(const float* __restrict__ src, u16* __restrict__ dst, int n) {
    int i = blockIdx.x * 256 + threadIdx.x;
    if (i < n) dst[i] = f2bf(src[i]);
}

// ---------- GEMM: C[b,row,p] = sum_c A[row,c] * Bt[b,p,c] + bias[row] ----------
template <bool OUT_F32>
__global__ __launch_bounds__(256) void k_gemm(const u16* __restrict__ A,
                                              const u16* __restrict__ Bt,
                                              void* __restrict__ Cout,
                                              const float* __restrict__ bias,
                                              int M) {
    __shared__ u16 As[128 * 32];
    __shared__ u16 Bs[128 * 32];
    const int tid = threadIdx.x;
    const int lane = tid & 63;
    const int wave = tid >> 6;
    const int wr = wave >> 1, wc = wave & 1;
    const int nb = blockIdx.x, mb = blockIdx.y, b = blockIdx.z;

    const u16* Ab = A + (size_t)(mb * 128) * 256;
    const u16* Bb = Bt + ((size_t)b * PTOT + (size_t)nb * 128) * 256;

    const int lrow = lane >> 2;
    const int lcol = (lane & 3) * 8;
    const int lr = lane & 15;
    const int lk = lane >> 4;

    f32x4 acc[4][4];
#pragma unroll
    for (int m = 0; m < 4; ++m)
#pragma unroll
        for (int n = 0; n < 4; ++n) acc[m][n] = (f32x4)0.f;

    for (int k0 = 0; k0 < 256; k0 += 32) {
        __syncthreads();
        const int i0 = wave * 2;
#pragma unroll
        for (int ii = 0; ii < 2; ++ii) {
            const int i = i0 + ii;
            ASYNC_COPY16(Ab + (size_t)(i * 16 + lrow) * 256 + k0 + lcol,
                         As + i * 16 * 32);
            ASYNC_COPY16(Bb + (size_t)(i * 16 + lrow) * 256 + k0 + lcol,
                         Bs + i * 16 * 32);
        }
        __syncthreads();
        const bf16x8* Asv = (const bf16x8*)As;
        const bf16x8* Bsv = (const bf16x8*)Bs;
        bf16x8 afr[4], bfr[4];
#pragma unroll
        for (int m = 0; m < 4; ++m)
            afr[m] = Asv[(wr * 64 + m * 16 + lr) * 4 + lk];
#pragma unroll
        for (int n = 0; n < 4; ++n)
            bfr[n] = Bsv[(wc * 64 + n * 16 + lr) * 4 + lk];
#pragma unroll
        for (int m = 0; m < 4; ++m)
#pragma unroll
            for (int n = 0; n < 4; ++n)
                acc[m][n] = __builtin_amdgcn_mfma_f32_16x16x32_bf16(
                    afr[m], bfr[n], acc[m][n], 0, 0, 0);
    }

    const int cr = (lane >> 4) * 4;
    const int cc = lane & 15;
#pragma unroll
    for (int m = 0; m < 4; ++m) {
#pragma unroll
        for (int j = 0; j < 4; ++j) {
            const int row = mb * 128 + wr * 64 + m * 16 + cr + j;
            const float bv = bias[row];
            const size_t rbase =
                ((size_t)b * M + row) * PTOT + (size_t)nb * 128 + wc * 64 + cc;
#pragma unroll
            for (int n = 0; n < 4; ++n) {
                const float v = acc[m][n][j] + bv;
                if (OUT_F32)
                    ((float*)Cout)[rbase + n * 16] = v;
                else
                    ((u16*)Cout)[rbase + n * 16] = f2bf(v);
            }
        }
    }
}

// ---------- depthwise 3x3, zero padding, 8 px x 2 rows per thread ----------
__global__ __launch_bounds__(256) void k_dwconv(const u16* __restrict__ in,
                                                u16* __restrict__ out,
                                                const float* __restrict__ w,
                                                const float* __restrict__ bias,
                                                int C) {
    const int vec = blockIdx.x * 256 + threadIdx.x;  // 0..2303 per (ch,img)
    const int ch = blockIdx.y, b = blockIdx.z;
    const int yg = vec / 24, xv = vec - yg * 24;     // yg: 0..95, 2 rows each
    const int y0 = yg * 2;
    const size_t base = ((size_t)(b * C + ch)) * PTOT;
    const float* wc9 = w + ch * 9;

    // load+convert 4 input rows (y0-1 .. y0+2) once; reuse for 2 output rows
    float p[4][10];
#pragma unroll
    for (int r = 0; r < 4; ++r) {
        const int yy = y0 - 1 + r;
        if ((unsigned)yy >= (unsigned)WIMG) {
#pragma unroll
            for (int i = 0; i < 10; ++i) p[r][i] = 0.f;
        } else {
            const u16* row = in + base + (size_t)yy * WIMG + xv * 8;
            const bf16x8 cv = *(const bf16x8*)row;
            p[r][0] = (xv > 0) ? bf2f(row[-1]) : 0.f;
            p[r][9] = (xv < 23) ? bf2f(row[8]) : 0.f;
#pragma unroll
            for (int i = 0; i < 8; ++i) p[r][i + 1] = bf2f((u16)cv[i]);
        }
    }

    const float bv = bias[ch];
#pragma unroll
    for (int r = 0; r < 2; ++r) {
        float acc[8];
#pragma unroll
        for (int i = 0; i < 8; ++i) acc[i] = bv;
#pragma unroll
        for (int dy = 0; dy < 3; ++dy) {
            const float wa = wc9[dy * 3], wbv = wc9[dy * 3 + 1], wcv = wc9[dy * 3 + 2];
            const float* pr = p[r + dy];
#pragma unroll
            for (int i = 0; i < 8; ++i)
                acc[i] += wa * pr[i] + wbv * pr[i + 1] + wcv * pr[i + 2];
        }
        bf16x8 ov;
#pragma unroll
        for (int i = 0; i < 8; ++i) ov[i] = (short)f2bf(acc[i]);
        *(bf16x8*)(out + base + (size_t)(y0 + r) * WIMG + xv * 8) = ov;
    }
}

// ---------- windowed channel cross-attention, 4 windows/block, MFMA ----------
// q: (2,256,P) bf16; kv: (2,512,P) bf16 (k2 ch 0..255, v2 ch 256..511)
// out: (2,P,256) bf16 pixel-major.  grid (144=24x6, 8, 2), 256 threads.
__global__ __launch_bounds__(256) void k_attn(const u16* __restrict__ q,
                                              const u16* __restrict__ kv,
                                              const float* __restrict__ temp,
                                              u16* __restrict__ outt) {
    // LDS map (u16 units): Q[0..9248) K[9248..18496) VT[18496..28768)
    // IQ f32 @28768, IK f32 @29024.  SS(f32) overlays K; P overlays Q.
    __shared__ __align__(16) u16 lds[29280];
    u16* Q = lds;                 // [w:2312][c:72-stride][64+8pad]
    u16* K = lds + 9248;
    u16* VT = lds + 18496;        // [w:2568][n:40-stride][32+8pad]
    float* IQ = (float*)(lds + 28768);
    float* IK = (float*)(lds + 29024);
    float* SS = (float*)(lds + 9248);  // [w:1156][c:36-stride][32]
    u16* P = lds;                      // [w:2312][c:40-stride][32]

    const int tid = threadIdx.x;
    const int lane = tid & 63;
    const int wv = tid >> 6;  // wave id == window id for MFMA phases
    const int h = blockIdx.y, b = blockIdx.z;
    const int wy = blockIdx.x / 6, wxg = blockIdx.x % 6;
    const int px0 = wxg * 32;

    const size_t qbase = ((size_t)b * 256 + h * 32) * PTOT;
    const size_t kbase = ((size_t)b * 512 + h * 32) * PTOT;
    const size_t vbase = kbase + (size_t)256 * PTOT;

    // ---- stage q,k row-major + v transposed ----
#pragma unroll
    for (int it = 0; it < 4; ++it) {
        const int L = it * 256 + tid;
        const int c = L >> 5, rem = L & 31, rr = rem >> 2, w = rem & 3;
        const size_t gp = (size_t)(wy * 8 + rr) * WIMG + px0 + w * 8;
        bf16x8 qv = *(const bf16x8*)(q + qbase + (size_t)c * PTOT + gp);
        bf16x8 kvv = *(const bf16x8*)(kv + kbase + (size_t)c * PTOT + gp);
        bf16x8 vv = *(const bf16x8*)(kv + vbase + (size_t)c * PTOT + gp);
        *(bf16x8*)(Q + w * 2312 + c * 72 + rr * 8) = qv;
        *(bf16x8*)(K + w * 2312 + c * 72 + rr * 8) = kvv;
        u16* vt = VT + w * 2568 + rr * 8 * 40 + c;
#pragma unroll
        for (int j = 0; j < 8; ++j) vt[j * 40] = (u16)vv[j];
    }
    __syncthreads();

    // ---- row l2-norms: t<128 -> q rows, t>=128 -> k rows ----
    {
        const int w = (tid >> 5) & 3, c = tid & 31;
        const u16* row = (tid < 128 ? Q : K) + w * 2312 + c * 72;
        float s = 0.f;
#pragma unroll
        for (int j = 0; j < 8; ++j) {
            bf16x8 v = *(const bf16x8*)(row + j * 8);
#pragma unroll
            for (int i = 0; i < 8; ++i) { float f = bf2f((u16)v[i]); s += f * f; }
        }
        const float inv = 1.f / fmaxf(sqrtf(s), 1e-12f);
        (tid < 128 ? IQ : IK)[w * 32 + c] = inv;
    }
    __syncthreads();

    // ---- scores: wave wv computes 32x32 raw dots for window wv ----
    {
        const int lr = lane & 15, lk = lane >> 4;
        f32x4 s00 = (f32x4)0.f, s01 = (f32x4)0.f, s10 = (f32x4)0.f, s11 = (f32x4)0.f;
        const u16* Qw = Q + wv * 2312 + lk * 8;
        const u16* Kw = K + wv * 2312 + lk * 8;
#pragma unroll
        for (int kb = 0; kb < 2; ++kb) {
            bf16x8 a0 = *(const bf16x8*)(Qw + lr * 72 + kb * 32);
            bf16x8 a1 = *(const bf16x8*)(Qw + (16 + lr) * 72 + kb * 32);
            bf16x8 b0 = *(const bf16x8*)(Kw + lr * 72 + kb * 32);
            bf16x8 b1 = *(const bf16x8*)(Kw + (16 + lr) * 72 + kb * 32);
            s00 = __builtin_amdgcn_mfma_f32_16x16x32_bf16(a0, b0, s00, 0, 0, 0);
            s01 = __builtin_amdgcn_mfma_f32_16x16x32_bf16(a0, b1, s01, 0, 0, 0);
            s10 = __builtin_amdgcn_mfma_f32_16x16x32_bf16(a1, b0, s10, 0, 0, 0);
            s11 = __builtin_amdgcn_mfma_f32_16x16x32_bf16(a1, b1, s11, 0, 0, 0);
        }
        float* srow = SS + wv * 1156;
        const int cr = lk * 4, cc = lr;
#pragma unroll
        for (int j = 0; j < 4; ++j) {
            srow[(cr + j) * 36 + cc] = s00[j];
            srow[(cr + j) * 36 + 16 + cc] = s01[j];
            srow[(16 + cr + j) * 36 + cc] = s10[j];
            srow[(16 + cr + j) * 36 + 16 + cc] = s11[j];
        }
    }
    __syncthreads();

    // ---- softmax: thread (w,c) owns one score row, fully in-register ----
    if (tid < 128) {
        const int w = tid >> 5, c = tid & 31;
        const float* srow = SS + w * 1156 + c * 36;
        const float* ik = IK + w * 32;
        const float iq = IQ[w * 32 + c] * temp[h];
        float sv[32];
        float mx = -1e30f;
#pragma unroll
        for (int d = 0; d < 32; ++d) {
            sv[d] = srow[d] * ik[d] * iq;
            mx = fmaxf(mx, sv[d]);
        }
        float sum = 0.f;
#pragma unroll
        for (int d = 0; d < 32; ++d) {
            sv[d] = __expf(sv[d] - mx);
            sum += sv[d];
        }
        const float inv = 1.f / sum;
        u16* prow = P + w * 2312 + c * 40;
#pragma unroll
        for (int ch = 0; ch < 4; ++ch) {
            bf16x8 pv;
#pragma unroll
            for (int i = 0; i < 8; ++i) pv[i] = (short)f2bf(sv[ch * 8 + i] * inv);
            *(bf16x8*)(prow + ch * 8) = pv;
        }
    }
    __syncthreads();

    // ---- PV: wave wv computes out 32x64 for window wv ----
    {
        const int lr = lane & 15, lk = lane >> 4;
        bf16x8 pa0 = *(const bf16x8*)(P + wv * 2312 + lr * 40 + lk * 8);
        bf16x8 pa1 = *(const bf16x8*)(P + wv * 2312 + (16 + lr) * 40 + lk * 8);
        f32x4 o0[4], o1[4];
#pragma unroll
        for (int ni = 0; ni < 4; ++ni) { o0[ni] = (f32x4)0.f; o1[ni] = (f32x4)0.f; }
#pragma unroll
        for (int ni = 0; ni < 4; ++ni) {
            bf16x8 vb = *(const bf16x8*)(VT + wv * 2568 + (ni * 16 + lr) * 40 + lk * 8);
            o0[ni] = __builtin_amdgcn_mfma_f32_16x16x32_bf16(pa0, vb, o0[ni], 0, 0, 0);
            o1[ni] = __builtin_amdgcn_mfma_f32_16x16x32_bf16(pa1, vb, o1[ni], 0, 0, 0);
        }
#pragma unroll
        for (int ni = 0; ni < 4; ++ni) {
            const int n = ni * 16 + lr;
            const size_t gp = (size_t)(wy * 8 + (n >> 3)) * WIMG + px0 + wv * 8 + (n & 7);
            u16* op = outt + ((size_t)b * PTOT + gp) * 256 + h * 32;
            u16x4 pk0, pk1;
#pragma unroll
            for (int j = 0; j < 4; ++j) { pk0[j] = f2bf(o0[ni][j]); pk1[j] = f2bf(o1[ni][j]); }
            *(u16x4*)(op + lk * 4) = pk0;
            *(u16x4*)(op + 16 + lk * 4) = pk1;
        }
    }
}

extern "C" void kernel_launch(void* const* d_in, const int* in_sizes, int n_in,
                              void* d_out, int out_size, void* d_ws, size_t ws_size,
                              hipStream_t stream) {
    (void)in_sizes; (void)n_in; (void)out_size; (void)ws_size;
    const float* x      = (const float*)d_in[0];
    const float* x2     = (const float*)d_in[1];
    const float* w_qkv  = (const float*)d_in[2];
    const float* b_qkv  = (const float*)d_in[3];
    const float* w_dw   = (const float*)d_in[4];
    const float* b_dw   = (const float*)d_in[5];
    const float* w_qkv2 = (const float*)d_in[6];
    const float* b_qkv2 = (const float*)d_in[7];
    const float* w_dw2  = (const float*)d_in[8];
    const float* b_dw2  = (const float*)d_in[9];
    const float* temp   = (const float*)d_in[10];
    const float* w_proj = (const float*)d_in[11];
    const float* b_proj = (const float*)d_in[12];
    float* out = (float*)d_out;

    char* ws = (char*)d_ws;
    const size_t SZ_T  = (size_t)2 * PTOT * 256 * 2;
    const size_t SZ_KV = (size_t)2 * PTOT * 512 * 2;
    u16* xt     = (u16*)(ws);
    u16* x2t    = (u16*)(ws + SZ_T);
    u16* qpre   = (u16*)(ws + 2 * SZ_T);
    u16* kvpre  = (u16*)(ws + 3 * SZ_T);
    u16* kvconv = (u16*)(ws + 3 * SZ_T + SZ_KV);
    u16* wq     = (u16*)(ws + 3 * SZ_T + 2 * SZ_KV);
    u16* wkv    = wq + 256 * 256;
    u16* wproj  = wkv + 512 * 256;
    u16* qconv  = xt;   // xt dead after q-GEMM
    u16* attnt  = x2t;  // x2t dead after kv-GEMM

    const dim3 tb(32, 8);
    k_transpose<<<dim3(PTOT / 32, 8, 2), tb, 0, stream>>>(x, xt);
    k_transpose<<<dim3(PTOT / 32, 8, 2), tb, 0, stream>>>(x2, x2t);
    k_f2bf<<<(256 * 256 + 255) / 256, 256, 0, stream>>>(w_qkv, wq, 256 * 256);
    k_f2bf<<<(512 * 256 + 255) / 256, 256, 0, stream>>>(w_qkv2 + 256 * 256, wkv, 512 * 256);
    k_f2bf<<<(256 * 256 + 255) / 256, 256, 0, stream>>>(w_proj, wproj, 256 * 256);

    k_gemm<false><<<dim3(PTOT / 128, 2, 2), 256, 0, stream>>>(wq, xt, qpre, b_qkv, 256);
    k_gemm<false><<<dim3(PTOT / 128, 4, 2), 256, 0, stream>>>(wkv, x2t, kvpre, b_qkv2 + 256, 512);

    k_dwconv<<<dim3(2304 / 256, 256, 2), 256, 0, stream>>>(qpre, qconv, w_dw, b_dw, 256);
    k_dwconv<<<dim3(2304 / 256, 512, 2), 256, 0, stream>>>(kvpre, kvconv, w_dw2 + 256 * 9, b_dw2 + 256, 512);

    k_attn<<<dim3(144, 8, 2), 256, 0, stream>>>(qconv, kvconv, temp, attnt);

    k_gemm<true><<<dim3(PTOT / 128, 2, 2), 256, 0, stream>>>(wproj, attnt, out, b_proj, 256);
}

// Round 8
// 241.115 us; speedup vs baseline: 1.6776x; 1.0239x over previous
//
#include <hip/hip_runtime.h>
#include <stdint.h>

typedef unsigned short u16;
typedef __attribute__((ext_vector_type(4))) unsigned short u16x4;
typedef __attribute__((ext_vector_type(8))) short bf16x8;
typedef __attribute__((ext_vector_type(4))) float f32x4;

#define PTOT 36864
#define WIMG 192

__device__ __forceinline__ float bf2f(u16 h) {
    union { uint32_t u; float f; } v; v.u = ((uint32_t)h) << 16; return v.f;
}
__device__ __forceinline__ u16 f2bf(float f) {
    union { float f; uint32_t u; } v; v.f = f;
    uint32_t u = v.u;
    return (u16)((u + 0x7FFFu + ((u >> 16) & 1u)) >> 16);
}

#define ASYNC_COPY16(gp, lp)                                                     \
    __builtin_amdgcn_global_load_lds(                                            \
        (const __attribute__((address_space(1))) void*)(gp),                     \
        (__attribute__((address_space(3))) void*)(lp), 16, 0, 0)

// ---------- transpose+convert: x (b,256,P) f32 -> xt (b,P,256) bf16 ----------
// 64x64 tiles: full 128B store lines, 256B load lines.
__global__ __launch_bounds__(256) void k_transpose(const float* __restrict__ x,
                                                   u16* __restrict__ xt) {
    __shared__ u16 tile[64][66];
    const int tx = threadIdx.x, ty = threadIdx.y;  // (64, 4)
    const int p0 = blockIdx.x * 64, c0 = blockIdx.y * 64, b = blockIdx.z;
    const float* src = x + (size_t)b * 256 * PTOT;
    u16* dst = xt + (size_t)b * PTOT * 256;
#pragma unroll
    for (int k = 0; k < 16; ++k) {
        const int c = c0 + ty + k * 4;
        tile[ty + k * 4][tx] = f2bf(src[(size_t)c * PTOT + p0 + tx]);
    }
    __syncthreads();
#pragma unroll
    for (int k = 0; k < 16; ++k) {
        const int p = p0 + ty + k * 4;
        dst[(size_t)p * 256 + c0 + tx] = tile[tx][ty + k * 4];
    }
}

// ---------- f32 -> bf16 for all three weight matrices (one launch) ----------
// dst: wq[65536] | wkv[131072] | wproj[65536] contiguous.
__global__ void k_f2bfAll(const float* __restrict__ w_qkv,
                          const float* __restrict__ w_qkv2,
                          const float* __restrict__ w_proj,
                          u16* __restrict__ dst) {
    const int i = blockIdx.x * 256 + threadIdx.x;  // 0..262143
    float v;
    if (i < 65536) v = w_qkv[i];
    else if (i < 196608) v = w_qkv2[i];          // rows 256..767 of w_qkv2
    else v = w_proj[i - 196608];
    dst[i] = f2bf(v);
}

// ---------- GEMM: C[b,row,p] = sum_c A[row,c] * Bt[b,p,c] + bias[row] ----------
template <bool OUT_F32>
__global__ __launch_bounds__(256) void k_gemm(const u16* __restrict__ A,
                                              const u16* __restrict__ Bt,
                                              void* __restrict__ Cout,
                                              const float* __restrict__ bias,
                                              int M) {
    __shared__ u16 As[128 * 32];
    __shared__ u16 Bs[128 * 32];
    const int tid = threadIdx.x;
    const int lane = tid & 63;
    const int wave = tid >> 6;
    const int wr = wave >> 1, wc = wave & 1;
    const int nb = blockIdx.x, mb = blockIdx.y, b = blockIdx.z;

    const u16* Ab = A + (size_t)(mb * 128) * 256;
    const u16* Bb = Bt + ((size_t)b * PTOT + (size_t)nb * 128) * 256;

    const int lrow = lane >> 2;
    const int lcol = (lane & 3) * 8;
    const int lr = lane & 15;
    const int lk = lane >> 4;

    f32x4 acc[4][4];
#pragma unroll
    for (int m = 0; m < 4; ++m)
#pragma unroll
        for (int n = 0; n < 4; ++n) acc[m][n] = (f32x4)0.f;

    for (int k0 = 0; k0 < 256; k0 += 32) {
        __syncthreads();
        const int i0 = wave * 2;
#pragma unroll
        for (int ii = 0; ii < 2; ++ii) {
            const int i = i0 + ii;
            ASYNC_COPY16(Ab + (size_t)(i * 16 + lrow) * 256 + k0 + lcol,
                         As + i * 16 * 32);
            ASYNC_COPY16(Bb + (size_t)(i * 16 + lrow) * 256 + k0 + lcol,
                         Bs + i * 16 * 32);
        }
        __syncthreads();
        const bf16x8* Asv = (const bf16x8*)As;
        const bf16x8* Bsv = (const bf16x8*)Bs;
        bf16x8 afr[4], bfr[4];
#pragma unroll
        for (int m = 0; m < 4; ++m)
            afr[m] = Asv[(wr * 64 + m * 16 + lr) * 4 + lk];
#pragma unroll
        for (int n = 0; n < 4; ++n)
            bfr[n] = Bsv[(wc * 64 + n * 16 + lr) * 4 + lk];
#pragma unroll
        for (int m = 0; m < 4; ++m)
#pragma unroll
            for (int n = 0; n < 4; ++n)
                acc[m][n] = __builtin_amdgcn_mfma_f32_16x16x32_bf16(
                    afr[m], bfr[n], acc[m][n], 0, 0, 0);
    }

    const int cr = (lane >> 4) * 4;
    const int cc = lane & 15;
#pragma unroll
    for (int m = 0; m < 4; ++m) {
#pragma unroll
        for (int j = 0; j < 4; ++j) {
            const int row = mb * 128 + wr * 64 + m * 16 + cr + j;
            const float bv = bias[row];
            const size_t rbase =
                ((size_t)b * M + row) * PTOT + (size_t)nb * 128 + wc * 64 + cc;
#pragma unroll
            for (int n = 0; n < 4; ++n) {
                const float v = acc[m][n][j] + bv;
                if (OUT_F32)
                    ((float*)Cout)[rbase + n * 16] = v;
                else
                    ((u16*)Cout)[rbase + n * 16] = f2bf(v);
            }
        }
    }
}

// ---------- depthwise 3x3, zero padding, 8 px x 2 rows per thread ----------
__global__ __launch_bounds__(256) void k_dwconv(const u16* __restrict__ in,
                                                u16* __restrict__ out,
                                                const float* __restrict__ w,
                                                const float* __restrict__ bias,
                                                int C) {
    const int vec = blockIdx.x * 256 + threadIdx.x;  // 0..2303 per (ch,img)
    const int ch = blockIdx.y, b = blockIdx.z;
    const int yg = vec / 24, xv = vec - yg * 24;
    const int y0 = yg * 2;
    const size_t base = ((size_t)(b * C + ch)) * PTOT;
    const float* wc9 = w + ch * 9;

    float p[4][10];
#pragma unroll
    for (int r = 0; r < 4; ++r) {
        const int yy = y0 - 1 + r;
        if ((unsigned)yy >= (unsigned)WIMG) {
#pragma unroll
            for (int i = 0; i < 10; ++i) p[r][i] = 0.f;
        } else {
            const u16* row = in + base + (size_t)yy * WIMG + xv * 8;
            const bf16x8 cv = *(const bf16x8*)row;
            p[r][0] = (xv > 0) ? bf2f(row[-1]) : 0.f;
            p[r][9] = (xv < 23) ? bf2f(row[8]) : 0.f;
#pragma unroll
            for (int i = 0; i < 8; ++i) p[r][i + 1] = bf2f((u16)cv[i]);
        }
    }

    const float bv = bias[ch];
#pragma unroll
    for (int r = 0; r < 2; ++r) {
        float acc[8];
#pragma unroll
        for (int i = 0; i < 8; ++i) acc[i] = bv;
#pragma unroll
        for (int dy = 0; dy < 3; ++dy) {
            const float wa = wc9[dy * 3], wbv = wc9[dy * 3 + 1], wcv = wc9[dy * 3 + 2];
            const float* pr = p[r + dy];
#pragma unroll
            for (int i = 0; i < 8; ++i)
                acc[i] += wa * pr[i] + wbv * pr[i + 1] + wcv * pr[i + 2];
        }
        bf16x8 ov;
#pragma unroll
        for (int i = 0; i < 8; ++i) ov[i] = (short)f2bf(acc[i]);
        *(bf16x8*)(out + base + (size_t)(y0 + r) * WIMG + xv * 8) = ov;
    }
}

// ---------- windowed channel cross-attention, 4 windows/block ----------
// Q/K fragments loaded DIRECTLY from global into registers (16B-contiguous);
// norms via shfl_xor; only V staged in LDS (transposed, XOR block-swizzled).
// LDS 38.5 KB -> 4 blocks/CU.  grid (144=24x6, 8, 2), 256 threads.
__global__ __launch_bounds__(256) void k_attn(const u16* __restrict__ q,
                                              const u16* __restrict__ kv,
                                              const float* __restrict__ temp,
                                              u16* __restrict__ outt) {
    // u16 units: VT[0,10272) SS(f32)@10272 (4x32x33) IQ@18720 IK@18976
    // P overlays SS (softmax: read SS -> barrier -> write P).
    __shared__ __align__(16) u16 lds[19232];
    u16* VT = lds;                       // [w:2568][n:40][32+8], blk-swizzled
    float* SS = (float*)(lds + 10272);   // [w:1056][c:33][32]
    u16* P = lds + 10272;                // [w:1280][c:40][32]
    float* IQ = (float*)(lds + 18720);
    float* IK = (float*)(lds + 18976);

    const int tid = threadIdx.x;
    const int lane = tid & 63;
    const int wv = tid >> 6;  // wave id == window id
    const int h = blockIdx.y, b = blockIdx.z;
    const int wy = blockIdx.x / 6, wxg = blockIdx.x % 6;
    const int px0 = wxg * 32;
    const int lr = lane & 15, lk = lane >> 4;

    const size_t qbase = ((size_t)b * 256 + h * 32) * PTOT;
    const size_t kbase = ((size_t)b * 512 + h * 32) * PTOT;
    const size_t vbase = kbase + (size_t)256 * PTOT;

    // ---- Q/K fragments direct from global: [kb][half] ----
    bf16x8 aq[2][2], bk[2][2];
#pragma unroll
    for (int kb = 0; kb < 2; ++kb) {
        const int rloc = kb * 4 + lk;
        const size_t gp = (size_t)(wy * 8 + rloc) * WIMG + px0 + wv * 8;
#pragma unroll
        for (int half = 0; half < 2; ++half) {
            const int ch = half * 16 + lr;
            aq[kb][half] = *(const bf16x8*)(q + qbase + (size_t)ch * PTOT + gp);
            bk[kb][half] = *(const bf16x8*)(kv + kbase + (size_t)ch * PTOT + gp);
        }
    }

    // ---- l2-norms in-register: reduce across the 4 lk-lanes of each lr ----
    {
        float sq0 = 0.f, sq1 = 0.f, sk0 = 0.f, sk1 = 0.f;
#pragma unroll
        for (int kb = 0; kb < 2; ++kb)
#pragma unroll
            for (int j = 0; j < 8; ++j) {
                float a0 = bf2f((u16)aq[kb][0][j]), a1 = bf2f((u16)aq[kb][1][j]);
                float k0 = bf2f((u16)bk[kb][0][j]), k1 = bf2f((u16)bk[kb][1][j]);
                sq0 += a0 * a0; sq1 += a1 * a1;
                sk0 += k0 * k0; sk1 += k1 * k1;
            }
        sq0 += __shfl_xor(sq0, 16); sq0 += __shfl_xor(sq0, 32);
        sq1 += __shfl_xor(sq1, 16); sq1 += __shfl_xor(sq1, 32);
        sk0 += __shfl_xor(sk0, 16); sk0 += __shfl_xor(sk0, 32);
        sk1 += __shfl_xor(sk1, 16); sk1 += __shfl_xor(sk1, 32);
        if (lk == 0) {
            IQ[wv * 32 + lr]      = 1.f / fmaxf(sqrtf(sq0), 1e-12f);
            IQ[wv * 32 + 16 + lr] = 1.f / fmaxf(sqrtf(sq1), 1e-12f);
            IK[wv * 32 + lr]      = 1.f / fmaxf(sqrtf(sk0), 1e-12f);
            IK[wv * 32 + 16 + lr] = 1.f / fmaxf(sqrtf(sk1), 1e-12f);
        }
    }

    // ---- stage V transposed (XOR block-swizzle kills 8-way conflicts) ----
#pragma unroll
    for (int it = 0; it < 4; ++it) {
        const int L = it * 256 + tid;
        const int c = L >> 5, rem = L & 31, rr = rem >> 2, w = rem & 3;
        const size_t gp = (size_t)(wy * 8 + rr) * WIMG + px0 + w * 8;
        bf16x8 vv = *(const bf16x8*)(kv + vbase + (size_t)c * PTOT + gp);
        const int blk = (c >> 3) ^ (rr & 3);  // n>>3 == rr for this write
        u16* vt = VT + w * 2568 + (rr * 8) * 40 + blk * 8 + (c & 7);
#pragma unroll
        for (int j = 0; j < 8; ++j) vt[j * 40] = (u16)vv[j];
    }
    __syncthreads();

    // ---- QK^T: wave wv computes 32x32 raw dots for window wv ----
    {
        f32x4 s00 = (f32x4)0.f, s01 = (f32x4)0.f, s10 = (f32x4)0.f, s11 = (f32x4)0.f;
#pragma unroll
        for (int kb = 0; kb < 2; ++kb) {
            s00 = __builtin_amdgcn_mfma_f32_16x16x32_bf16(aq[kb][0], bk[kb][0], s00, 0, 0, 0);
            s01 = __builtin_amdgcn_mfma_f32_16x16x32_bf16(aq[kb][0], bk[kb][1], s01, 0, 0, 0);
            s10 = __builtin_amdgcn_mfma_f32_16x16x32_bf16(aq[kb][1], bk[kb][0], s10, 0, 0, 0);
            s11 = __builtin_amdgcn_mfma_f32_16x16x32_bf16(aq[kb][1], bk[kb][1], s11, 0, 0, 0);
        }
        float* srow = SS + wv * 1056;
        const int cr = lk * 4, cc = lr;
#pragma unroll
        for (int j = 0; j < 4; ++j) {
            srow[(cr + j) * 33 + cc] = s00[j];
            srow[(cr + j) * 33 + 16 + cc] = s01[j];
            srow[(16 + cr + j) * 33 + cc] = s10[j];
            srow[(16 + cr + j) * 33 + 16 + cc] = s11[j];
        }
    }
    __syncthreads();

    // ---- softmax: read SS -> regs, barrier, write P (P overlays SS) ----
    float sv[32];
    float pinv = 0.f;
    const int sw = tid >> 5, sc = tid & 31;
    if (tid < 128) {
        const float* srow = SS + sw * 1056 + sc * 33;
        const float* ik = IK + sw * 32;
        const float iq = IQ[sw * 32 + sc] * temp[h];
        float mx = -1e30f;
#pragma unroll
        for (int d = 0; d < 32; ++d) {
            sv[d] = srow[d] * ik[d] * iq;
            mx = fmaxf(mx, sv[d]);
        }
        float sum = 0.f;
#pragma unroll
        for (int d = 0; d < 32; ++d) {
            sv[d] = __expf(sv[d] - mx);
            sum += sv[d];
        }
        pinv = 1.f / sum;
    }
    __syncthreads();
    if (tid < 128) {
        u16* prow = P + sw * 1280 + sc * 40;
#pragma unroll
        for (int ch = 0; ch < 4; ++ch) {
            bf16x8 pv;
#pragma unroll
            for (int i = 0; i < 8; ++i) pv[i] = (short)f2bf(sv[ch * 8 + i] * pinv);
            *(bf16x8*)(prow + ch * 8) = pv;
        }
    }
    __syncthreads();

    // ---- PV: wave wv computes out 32x64 for window wv ----
    {
        bf16x8 pa0 = *(const bf16x8*)(P + wv * 1280 + lr * 40 + lk * 8);
        bf16x8 pa1 = *(const bf16x8*)(P + wv * 1280 + (16 + lr) * 40 + lk * 8);
        f32x4 o0[4], o1[4];
#pragma unroll
        for (int ni = 0; ni < 4; ++ni) { o0[ni] = (f32x4)0.f; o1[ni] = (f32x4)0.f; }
#pragma unroll
        for (int ni = 0; ni < 4; ++ni) {
            const int n = ni * 16 + lr;
            const int blkr = lk ^ ((ni * 2 + (lr >> 3)) & 3);  // (n>>3)&3
            bf16x8 vb = *(const bf16x8*)(VT + wv * 2568 + n * 40 + blkr * 8);
            o0[ni] = __builtin_amdgcn_mfma_f32_16x16x32_bf16(pa0, vb, o0[ni], 0, 0, 0);
            o1[ni] = __builtin_amdgcn_mfma_f32_16x16x32_bf16(pa1, vb, o1[ni], 0, 0, 0);
        }
#pragma unroll
        for (int ni = 0; ni < 4; ++ni) {
            const int n = ni * 16 + lr;
            const size_t gp = (size_t)(wy * 8 + (n >> 3)) * WIMG + px0 + wv * 8 + (n & 7);
            u16* op = outt + ((size_t)b * PTOT + gp) * 256 + h * 32;
            u16x4 pk0, pk1;
#pragma unroll
            for (int j = 0; j < 4; ++j) { pk0[j] = f2bf(o0[ni][j]); pk1[j] = f2bf(o1[ni][j]); }
            *(u16x4*)(op + lk * 4) = pk0;
            *(u16x4*)(op + 16 + lk * 4) = pk1;
        }
    }
}

extern "C" void kernel_launch(void* const* d_in, const int* in_sizes, int n_in,
                              void* d_out, int out_size, void* d_ws, size_t ws_size,
                              hipStream_t stream) {
    (void)in_sizes; (void)n_in; (void)out_size; (void)ws_size;
    const float* x      = (const float*)d_in[0];
    const float* x2     = (const float*)d_in[1];
    const float* w_qkv  = (const float*)d_in[2];
    const float* b_qkv  = (const float*)d_in[3];
    const float* w_dw   = (const float*)d_in[4];
    const float* b_dw   = (const float*)d_in[5];
    const float* w_qkv2 = (const float*)d_in[6];
    const float* b_qkv2 = (const float*)d_in[7];
    const float* w_dw2  = (const float*)d_in[8];
    const float* b_dw2  = (const float*)d_in[9];
    const float* temp   = (const float*)d_in[10];
    const float* w_proj = (const float*)d_in[11];
    const float* b_proj = (const float*)d_in[12];
    float* out = (float*)d_out;

    char* ws = (char*)d_ws;
    const size_t SZ_T  = (size_t)2 * PTOT * 256 * 2;
    const size_t SZ_KV = (size_t)2 * PTOT * 512 * 2;
    u16* xt     = (u16*)(ws);
    u16* x2t    = (u16*)(ws + SZ_T);
    u16* qpre   = (u16*)(ws + 2 * SZ_T);
    u16* kvpre  = (u16*)(ws + 3 * SZ_T);
    u16* kvconv = (u16*)(ws + 3 * SZ_T + SZ_KV);
    u16* wq     = (u16*)(ws + 3 * SZ_T + 2 * SZ_KV);
    u16* wkv    = wq + 256 * 256;
    u16* wproj  = wkv + 512 * 256;
    u16* qconv  = xt;   // xt dead after q-GEMM
    u16* attnt  = x2t;  // x2t dead after kv-GEMM

    const dim3 tb(64, 4);
    k_transpose<<<dim3(PTOT / 64, 4, 2), tb, 0, stream>>>(x, xt);
    k_transpose<<<dim3(PTOT / 64, 4, 2), tb, 0, stream>>>(x2, x2t);
    k_f2bfAll<<<262144 / 256, 256, 0, stream>>>(w_qkv, w_qkv2, w_proj, wq);

    k_gemm<false><<<dim3(PTOT / 128, 2, 2), 256, 0, stream>>>(wq, xt, qpre, b_qkv, 256);
    k_gemm<false><<<dim3(PTOT / 128, 4, 2), 256, 0, stream>>>(wkv, x2t, kvpre, b_qkv2 + 256, 512);

    k_dwconv<<<dim3(2304 / 256, 256, 2), 256, 0, stream>>>(qpre, qconv, w_dw, b_dw, 256);
    k_dwconv<<<dim3(2304 / 256, 512, 2), 256, 0, stream>>>(kvpre, kvconv, w_dw2 + 256 * 9, b_dw2 + 256, 512);

    k_attn<<<dim3(144, 8, 2), 256, 0, stream>>>(qconv, kvconv, temp, attnt);

    k_gemm<true><<<dim3(PTOT / 128, 2, 2), 256, 0, stream>>>(wproj, attnt, out, b_proj, 256);
}